// Round 1
// baseline (840.778 us; speedup 1.0000x reference)
//
#include <hip/hip_runtime.h>
#include <math.h>

#define BATCH 4
#define SEQ   1024
#define CH    1024
#define NH    16
#define HD    64
#define N3    3072

// ---------------------------------------------------------------------------
// GEMM 1: qkv = x @ Wqkv, scatter into q/k/v [B][H][T][HD] fp32
// 64x64 tile, 256 threads, 4x4 per-thread microtile, BK=16
// ---------------------------------------------------------------------------
__global__ __launch_bounds__(256) void gemm_qkv_kernel(
    const float* __restrict__ X, const float* __restrict__ W,
    float* __restrict__ qw, float* __restrict__ kw, float* __restrict__ vw)
{
    __shared__ float As[16][68];   // As[k][m], stride 68 -> 16B-aligned rows, 2-way-max write conflicts
    __shared__ float Bs[16][64];   // Bs[k][n]

    const int tid = threadIdx.x;
    const int tx = tid & 15;       // n subtile
    const int ty = tid >> 4;       // m subtile
    const int m0 = blockIdx.y * 64;
    const int n0 = blockIdx.x * 64;

    const int lm = tid >> 2;         // 0..63 row for A load
    const int lk = (tid & 3) << 2;   // k chunk for A load
    const int brow = tid >> 4;       // 0..15 k row for B load
    const int bcol = (tid & 15) << 2;

    float acc[4][4];
    #pragma unroll
    for (int i = 0; i < 4; i++)
        #pragma unroll
        for (int j = 0; j < 4; j++) acc[i][j] = 0.f;

    for (int k0 = 0; k0 < CH; k0 += 16) {
        float4 av = *(const float4*)&X[(size_t)(m0 + lm) * CH + k0 + lk];
        float4 bv = *(const float4*)&W[(size_t)(k0 + brow) * N3 + n0 + bcol];
        __syncthreads();
        As[lk + 0][lm] = av.x;
        As[lk + 1][lm] = av.y;
        As[lk + 2][lm] = av.z;
        As[lk + 3][lm] = av.w;
        *(float4*)&Bs[brow][bcol] = bv;
        __syncthreads();
        #pragma unroll
        for (int kk = 0; kk < 16; ++kk) {
            float4 a = *(const float4*)&As[kk][ty << 2];
            float4 b = *(const float4*)&Bs[kk][tx << 2];
            float am[4] = {a.x, a.y, a.z, a.w};
            float bn[4] = {b.x, b.y, b.z, b.w};
            #pragma unroll
            for (int i = 0; i < 4; i++)
                #pragma unroll
                for (int j = 0; j < 4; j++)
                    acc[i][j] = fmaf(am[i], bn[j], acc[i][j]);
        }
    }

    // epilogue: scatter n -> (which, h, d); all 4 cols share which/h (64-aligned tiles)
    const int n = n0 + (tx << 2);
    const int which = n >> 10;
    const int c = n & 1023;
    const int h = c >> 6;
    const int d = c & 63;
    float* dst = (which == 0) ? qw : (which == 1) ? kw : vw;
    #pragma unroll
    for (int i = 0; i < 4; i++) {
        int m = m0 + (ty << 2) + i;
        int b = m >> 10;
        int t = m & 1023;
        size_t off = (((size_t)(b * NH + h)) * SEQ + t) * HD + d;
        *(float4*)&dst[off] = make_float4(acc[i][0], acc[i][1], acc[i][2], acc[i][3]);
    }
}

// ---------------------------------------------------------------------------
// GEMM 2: out = y_attn @ Wproj  (direct to d_out, row-major [4096][1024])
// ---------------------------------------------------------------------------
__global__ __launch_bounds__(256) void gemm_proj_kernel(
    const float* __restrict__ X, const float* __restrict__ W, float* __restrict__ out)
{
    __shared__ float As[16][68];
    __shared__ float Bs[16][64];

    const int tid = threadIdx.x;
    const int tx = tid & 15;
    const int ty = tid >> 4;
    const int m0 = blockIdx.y * 64;
    const int n0 = blockIdx.x * 64;

    const int lm = tid >> 2;
    const int lk = (tid & 3) << 2;
    const int brow = tid >> 4;
    const int bcol = (tid & 15) << 2;

    float acc[4][4];
    #pragma unroll
    for (int i = 0; i < 4; i++)
        #pragma unroll
        for (int j = 0; j < 4; j++) acc[i][j] = 0.f;

    for (int k0 = 0; k0 < CH; k0 += 16) {
        float4 av = *(const float4*)&X[(size_t)(m0 + lm) * CH + k0 + lk];
        float4 bv = *(const float4*)&W[(size_t)(k0 + brow) * CH + n0 + bcol];
        __syncthreads();
        As[lk + 0][lm] = av.x;
        As[lk + 1][lm] = av.y;
        As[lk + 2][lm] = av.z;
        As[lk + 3][lm] = av.w;
        *(float4*)&Bs[brow][bcol] = bv;
        __syncthreads();
        #pragma unroll
        for (int kk = 0; kk < 16; ++kk) {
            float4 a = *(const float4*)&As[kk][ty << 2];
            float4 b = *(const float4*)&Bs[kk][tx << 2];
            float am[4] = {a.x, a.y, a.z, a.w};
            float bn[4] = {b.x, b.y, b.z, b.w};
            #pragma unroll
            for (int i = 0; i < 4; i++)
                #pragma unroll
                for (int j = 0; j < 4; j++)
                    acc[i][j] = fmaf(am[i], bn[j], acc[i][j]);
        }
    }

    const int n = n0 + (tx << 2);
    #pragma unroll
    for (int i = 0; i < 4; i++) {
        int m = m0 + (ty << 2) + i;
        *(float4*)&out[(size_t)m * CH + n] =
            make_float4(acc[i][0], acc[i][1], acc[i][2], acc[i][3]);
    }
}

// ---------------------------------------------------------------------------
// Attention: block = (b, h, 64 query rows). 256 thr = 32 row-groups x 8 dim-lanes,
// 2 rows/thread. K/V tiles (64x64 fp32) staged in LDS. Banded causal j-loop.
// ---------------------------------------------------------------------------
__global__ __launch_bounds__(256) void attn_kernel(
    const float* __restrict__ qw, const float* __restrict__ kw,
    const float* __restrict__ vw,
    const float* __restrict__ span_params, const float* __restrict__ stride_params,
    float* __restrict__ yw)
{
    __shared__ float Ks[64][64];
    __shared__ float Vs[64][64];

    const int tid = threadIdx.x;
    const int g  = tid & 7;        // dim group: dims g*8 .. g*8+7
    const int rl = tid >> 3;       // 0..31
    const int blk = blockIdx.x;    // (b*NH + h)*16 + it
    const int it  = blk & 15;
    const int bh  = blk >> 4;
    const int h   = bh & (NH - 1);
    const int b   = bh >> 4;
    const int it0 = it << 6;

    const float span  = 1024.f / (1.f + __expf(-span_params[h]));
    const float limit = 32.f + span;                 // mask nonzero iff rel < limit
    const float e0 = __expf(stride_params[2 * h + 0]);
    const float e1 = __expf(stride_params[2 * h + 1]);
    const float inv_e = 1.f / (e0 + e1);
    const float sw0 = e0 * inv_e, sw1 = e1 * inv_e;

    const float* qg = qw + (size_t)bh * SEQ * HD;
    const float* kg = kw + (size_t)bh * SEQ * HD;
    const float* vg = vw + (size_t)bh * SEQ * HD;

    const int i0 = it0 + rl;
    const int i1 = it0 + rl + 32;

    float q0[8], q1[8];
    {
        const float4* p0 = (const float4*)&qg[(size_t)i0 * HD + g * 8];
        float4 a = p0[0], bb = p0[1];
        q0[0] = a.x; q0[1] = a.y; q0[2] = a.z; q0[3] = a.w;
        q0[4] = bb.x; q0[5] = bb.y; q0[6] = bb.z; q0[7] = bb.w;
        const float4* p1 = (const float4*)&qg[(size_t)i1 * HD + g * 8];
        float4 c = p1[0], dd = p1[1];
        q1[0] = c.x; q1[1] = c.y; q1[2] = c.z; q1[3] = c.w;
        q1[4] = dd.x; q1[5] = dd.y; q1[6] = dd.z; q1[7] = dd.w;
    }

    float acc0[8], acc1[8];
    #pragma unroll
    for (int i = 0; i < 8; i++) { acc0[i] = 0.f; acc1[i] = 0.f; }
    float sum0 = 0.f, sum1 = 0.f;

    int jmin = it0 - (int)limit - 1;
    if (jmin < 0) jmin = 0;
    const int jt0 = jmin & ~63;

    for (int jt = jt0; jt < it0 + 64; jt += 64) {
        __syncthreads();
        #pragma unroll
        for (int p = 0; p < 4; p++) {
            int o  = (tid + (p << 8)) << 2;
            int jj = o >> 6;
            int dd = o & 63;
            *(float4*)&Ks[jj][dd] = *(const float4*)&kg[(size_t)(jt + jj) * HD + dd];
            *(float4*)&Vs[jj][dd] = *(const float4*)&vg[(size_t)(jt + jj) * HD + dd];
        }
        __syncthreads();

        const int jend = min(jt + 64, it0 + 64);
        for (int j = jt; j < jend; ++j) {
            const int jj = j - jt;
            const float4* kr = (const float4*)&Ks[jj][g * 8];
            float4 ka = kr[0], kb = kr[1];
            float d0 = q0[0] * ka.x + q0[1] * ka.y + q0[2] * ka.z + q0[3] * ka.w
                     + q0[4] * kb.x + q0[5] * kb.y + q0[6] * kb.z + q0[7] * kb.w;
            float d1 = q1[0] * ka.x + q1[1] * ka.y + q1[2] * ka.z + q1[3] * ka.w
                     + q1[4] * kb.x + q1[5] * kb.y + q1[6] * kb.z + q1[7] * kb.w;
            // 8-lane butterfly (lanes rl*8+g, xor flips only g bits)
            d0 += __shfl_xor(d0, 1); d0 += __shfl_xor(d0, 2); d0 += __shfl_xor(d0, 4);
            d1 += __shfl_xor(d1, 1); d1 += __shfl_xor(d1, 2); d1 += __shfl_xor(d1, 4);

            float w0 = 0.f, w1 = 0.f;
            const int rel0 = i0 - j;
            if (rel0 >= 0) {
                float clipv = fminf(fmaxf((limit - (float)rel0) * (1.f / 32.f), 0.f), 1.f);
                float m2 = ((rel0 & 1) == 0) ? clipv : 0.f;
                w0 = __expf(d0 * 0.125f) * (sw0 * clipv + sw1 * m2);
            }
            const int rel1 = i1 - j;
            if (rel1 >= 0) {
                float clipv = fminf(fmaxf((limit - (float)rel1) * (1.f / 32.f), 0.f), 1.f);
                float m2 = ((rel1 & 1) == 0) ? clipv : 0.f;
                w1 = __expf(d1 * 0.125f) * (sw0 * clipv + sw1 * m2);
            }

            const float4* vr = (const float4*)&Vs[jj][g * 8];
            float4 va = vr[0], vb = vr[1];
            acc0[0] = fmaf(w0, va.x, acc0[0]); acc0[1] = fmaf(w0, va.y, acc0[1]);
            acc0[2] = fmaf(w0, va.z, acc0[2]); acc0[3] = fmaf(w0, va.w, acc0[3]);
            acc0[4] = fmaf(w0, vb.x, acc0[4]); acc0[5] = fmaf(w0, vb.y, acc0[5]);
            acc0[6] = fmaf(w0, vb.z, acc0[6]); acc0[7] = fmaf(w0, vb.w, acc0[7]);
            acc1[0] = fmaf(w1, va.x, acc1[0]); acc1[1] = fmaf(w1, va.y, acc1[1]);
            acc1[2] = fmaf(w1, va.z, acc1[2]); acc1[3] = fmaf(w1, va.w, acc1[3]);
            acc1[4] = fmaf(w1, vb.x, acc1[4]); acc1[5] = fmaf(w1, vb.y, acc1[5]);
            acc1[6] = fmaf(w1, vb.z, acc1[6]); acc1[7] = fmaf(w1, vb.w, acc1[7]);
            sum0 += w0; sum1 += w1;
        }
    }

    const float r0 = 1.f / sum0;
    const float r1 = 1.f / sum1;
    // store y_attn in [B][T][C] (row-major for proj GEMM)
    const size_t base0 = ((size_t)(b * SEQ + i0)) * CH + h * HD + g * 8;
    const size_t base1 = ((size_t)(b * SEQ + i1)) * CH + h * HD + g * 8;
    *(float4*)&yw[base0]     = make_float4(acc0[0] * r0, acc0[1] * r0, acc0[2] * r0, acc0[3] * r0);
    *(float4*)&yw[base0 + 4] = make_float4(acc0[4] * r0, acc0[5] * r0, acc0[6] * r0, acc0[7] * r0);
    *(float4*)&yw[base1]     = make_float4(acc1[0] * r1, acc1[1] * r1, acc1[2] * r1, acc1[3] * r1);
    *(float4*)&yw[base1 + 4] = make_float4(acc1[4] * r1, acc1[5] * r1, acc1[6] * r1, acc1[7] * r1);
}

// ---------------------------------------------------------------------------
// span_loss = SPAN_REG * sum(sigmoid(span_params)*MAX_SPAN) / H
// ---------------------------------------------------------------------------
__global__ void span_loss_kernel(const float* __restrict__ sp, float* __restrict__ out)
{
    if (threadIdx.x == 0 && blockIdx.x == 0) {
        float s = 0.f;
        for (int h = 0; h < NH; h++) {
            float sig = 1.f / (1.f + __expf(-sp[h]));
            s += sig * 1024.f;
        }
        out[0] = 2e-6f * s / (float)NH;
    }
}

extern "C" void kernel_launch(void* const* d_in, const int* in_sizes, int n_in,
                              void* d_out, int out_size, void* d_ws, size_t ws_size,
                              hipStream_t stream)
{
    const float* x            = (const float*)d_in[0];
    const float* Wqkv         = (const float*)d_in[1];
    const float* Wproj        = (const float*)d_in[2];
    const float* span_params  = (const float*)d_in[3];
    const float* stride_param = (const float*)d_in[4];
    float* out = (float*)d_out;

    float* ws = (float*)d_ws;
    const size_t SZ = (size_t)BATCH * NH * SEQ * HD;  // 4,194,304 elements
    float* qw = ws;
    float* kw = ws + SZ;
    float* vw = ws + 2 * SZ;
    float* yw = ws + 3 * SZ;   // [B][T][C]

    dim3 g1(N3 / 64, (BATCH * SEQ) / 64);
    gemm_qkv_kernel<<<g1, 256, 0, stream>>>(x, Wqkv, qw, kw, vw);

    attn_kernel<<<dim3(BATCH * NH * (SEQ / 64)), 256, 0, stream>>>(
        qw, kw, vw, span_params, stride_param, yw);

    dim3 g2(CH / 64, (BATCH * SEQ) / 64);
    gemm_proj_kernel<<<g2, 256, 0, stream>>>(yw, Wproj, out);

    span_loss_kernel<<<1, 64, 0, stream>>>(span_params, out + SZ);
}

// Round 2
// 460.264 us; speedup vs baseline: 1.8267x; 1.8267x over previous
//
#include <hip/hip_runtime.h>
#include <math.h>

#define BATCH 4
#define SEQ   1024
#define CH    1024
#define NH    16
#define HD    64
#define N3    3072

typedef unsigned short u16;
typedef unsigned int   u32;
typedef __attribute__((ext_vector_type(8))) __bf16 bf16x8;
typedef __attribute__((ext_vector_type(4))) float  f32x4;

__device__ __forceinline__ u32 f2bf(float f) {
    u32 x = __float_as_uint(f);
    return (x + 0x7fffu + ((x >> 16) & 1u)) >> 16;   // RNE bf16
}

// ---------------------------------------------------------------------------
// fp32 -> bf16 elementwise (8 elems/thread)
// ---------------------------------------------------------------------------
__global__ __launch_bounds__(256) void conv_bf16_kernel(
    const float* __restrict__ in, u16* __restrict__ out, int n)
{
    int i = (blockIdx.x * 256 + threadIdx.x) * 8;
    if (i >= n) return;
    float4 a = *(const float4*)&in[i];
    float4 b = *(const float4*)&in[i + 4];
    int4 p;
    p.x = (int)(f2bf(a.x) | (f2bf(a.y) << 16));
    p.y = (int)(f2bf(a.z) | (f2bf(a.w) << 16));
    p.z = (int)(f2bf(b.x) | (f2bf(b.y) << 16));
    p.w = (int)(f2bf(b.z) | (f2bf(b.w) << 16));
    *(int4*)&out[i] = p;
}

// ---------------------------------------------------------------------------
// W [K][N] fp32 -> WT [N][K] bf16  (32x32 LDS tile transpose)
// ---------------------------------------------------------------------------
__global__ __launch_bounds__(256) void transpose_conv_kernel(
    const float* __restrict__ W, u16* __restrict__ WT, int K, int N)
{
    __shared__ float tile[32][33];
    const int n0 = blockIdx.x * 32, k0 = blockIdx.y * 32;
    const int tx = threadIdx.x & 31, ty = threadIdx.x >> 5;
    #pragma unroll
    for (int p = 0; p < 4; p++)
        tile[ty + p * 8][tx] = W[(size_t)(k0 + ty + p * 8) * N + n0 + tx];
    __syncthreads();
    #pragma unroll
    for (int p = 0; p < 4; p++)
        WT[(size_t)(n0 + ty + p * 8) * K + k0 + tx] = (u16)f2bf(tile[tx][ty + p * 8]);
}

// ---------------------------------------------------------------------------
// MFMA GEMM core: 128x128 tile, 256 thr (4 waves, 2x2), BK=32, 16x16x32 bf16.
// A [M][1024] bf16 row-major; BT [N][1024] bf16 row-major (B transposed).
// Verified layouts: A-frag lane=(m=l&15, k=quad*8+j); B-frag (n=l&15, k=quad*8+j);
// C/D col=l&15, row=quad*4+reg.
// ---------------------------------------------------------------------------
__global__ __launch_bounds__(256) void gemm_qkv_mfma(
    const u16* __restrict__ A, const u16* __restrict__ BT,
    float* __restrict__ qw, float* __restrict__ kw, float* __restrict__ vw)
{
    __shared__ __align__(16) u16 As[128 * 32];
    __shared__ __align__(16) u16 Bs[128 * 32];

    const int tid = threadIdx.x;
    const int lane = tid & 63;
    const int w = tid >> 6;
    const int wr = w >> 1, wc = w & 1;
    const int m0 = blockIdx.y * 128, n0 = blockIdx.x * 128;

    const int sr = tid >> 2;            // 0..63
    const int sc = (tid & 3) * 8;       // bf16 col within 32
    const u16* Ag0 = A  + (size_t)(m0 + sr) * CH + sc;
    const u16* Ag1 = A  + (size_t)(m0 + 64 + sr) * CH + sc;
    const u16* Bg0 = BT + (size_t)(n0 + sr) * CH + sc;
    const u16* Bg1 = BT + (size_t)(n0 + 64 + sr) * CH + sc;

    const int ln = lane & 15, quad = lane >> 4;
    const int afo = (wr * 64 + ln) * 32 + quad * 8;   // + mi*16*32
    const int bfo = (wc * 64 + ln) * 32 + quad * 8;   // + ni*16*32

    f32x4 acc[4][4];
    #pragma unroll
    for (int i = 0; i < 4; i++)
        #pragma unroll
        for (int j = 0; j < 4; j++) acc[i][j] = (f32x4)(0.f);

    for (int k0 = 0; k0 < CH; k0 += 32) {
        int4 a0 = *(const int4*)(Ag0 + k0);
        int4 a1 = *(const int4*)(Ag1 + k0);
        int4 b0 = *(const int4*)(Bg0 + k0);
        int4 b1 = *(const int4*)(Bg1 + k0);
        __syncthreads();
        *(int4*)&As[sr * 32 + sc]        = a0;
        *(int4*)&As[(sr + 64) * 32 + sc] = a1;
        *(int4*)&Bs[sr * 32 + sc]        = b0;
        *(int4*)&Bs[(sr + 64) * 32 + sc] = b1;
        __syncthreads();
        bf16x8 af[4], bfr[4];
        #pragma unroll
        for (int mi = 0; mi < 4; mi++) af[mi]  = *(const bf16x8*)&As[afo + mi * 512];
        #pragma unroll
        for (int ni = 0; ni < 4; ni++) bfr[ni] = *(const bf16x8*)&Bs[bfo + ni * 512];
        #pragma unroll
        for (int mi = 0; mi < 4; mi++)
            #pragma unroll
            for (int ni = 0; ni < 4; ni++)
                acc[mi][ni] = __builtin_amdgcn_mfma_f32_16x16x32_bf16(
                    af[mi], bfr[ni], acc[mi][ni], 0, 0, 0);
    }

    // scatter epilogue into q/k/v [B][H][T][64]
    #pragma unroll
    for (int ni = 0; ni < 4; ni++) {
        const int n = n0 + wc * 64 + ni * 16 + ln;
        const int which = n >> 10;
        const int h = (n >> 6) & 15;
        const int d = n & 63;
        float* dst = (which == 0) ? qw : (which == 1) ? kw : vw;
        #pragma unroll
        for (int mi = 0; mi < 4; mi++) {
            #pragma unroll
            for (int r = 0; r < 4; r++) {
                const int m = m0 + wr * 64 + mi * 16 + quad * 4 + r;
                const int b = m >> 10, t = m & 1023;
                dst[(((size_t)(b * NH + h)) * SEQ + t) * HD + d] = acc[mi][ni][r];
            }
        }
    }
}

__global__ __launch_bounds__(256) void gemm_proj_mfma(
    const u16* __restrict__ A, const u16* __restrict__ BT, float* __restrict__ out)
{
    __shared__ __align__(16) u16 As[128 * 32];
    __shared__ __align__(16) u16 Bs[128 * 32];

    const int tid = threadIdx.x;
    const int lane = tid & 63;
    const int w = tid >> 6;
    const int wr = w >> 1, wc = w & 1;
    const int m0 = blockIdx.y * 128, n0 = blockIdx.x * 128;

    const int sr = tid >> 2;
    const int sc = (tid & 3) * 8;
    const u16* Ag0 = A  + (size_t)(m0 + sr) * CH + sc;
    const u16* Ag1 = A  + (size_t)(m0 + 64 + sr) * CH + sc;
    const u16* Bg0 = BT + (size_t)(n0 + sr) * CH + sc;
    const u16* Bg1 = BT + (size_t)(n0 + 64 + sr) * CH + sc;

    const int ln = lane & 15, quad = lane >> 4;
    const int afo = (wr * 64 + ln) * 32 + quad * 8;
    const int bfo = (wc * 64 + ln) * 32 + quad * 8;

    f32x4 acc[4][4];
    #pragma unroll
    for (int i = 0; i < 4; i++)
        #pragma unroll
        for (int j = 0; j < 4; j++) acc[i][j] = (f32x4)(0.f);

    for (int k0 = 0; k0 < CH; k0 += 32) {
        int4 a0 = *(const int4*)(Ag0 + k0);
        int4 a1 = *(const int4*)(Ag1 + k0);
        int4 b0 = *(const int4*)(Bg0 + k0);
        int4 b1 = *(const int4*)(Bg1 + k0);
        __syncthreads();
        *(int4*)&As[sr * 32 + sc]        = a0;
        *(int4*)&As[(sr + 64) * 32 + sc] = a1;
        *(int4*)&Bs[sr * 32 + sc]        = b0;
        *(int4*)&Bs[(sr + 64) * 32 + sc] = b1;
        __syncthreads();
        bf16x8 af[4], bfr[4];
        #pragma unroll
        for (int mi = 0; mi < 4; mi++) af[mi]  = *(const bf16x8*)&As[afo + mi * 512];
        #pragma unroll
        for (int ni = 0; ni < 4; ni++) bfr[ni] = *(const bf16x8*)&Bs[bfo + ni * 512];
        #pragma unroll
        for (int mi = 0; mi < 4; mi++)
            #pragma unroll
            for (int ni = 0; ni < 4; ni++)
                acc[mi][ni] = __builtin_amdgcn_mfma_f32_16x16x32_bf16(
                    af[mi], bfr[ni], acc[mi][ni], 0, 0, 0);
    }

    #pragma unroll
    for (int ni = 0; ni < 4; ni++) {
        const int n = n0 + wc * 64 + ni * 16 + ln;
        #pragma unroll
        for (int mi = 0; mi < 4; mi++) {
            #pragma unroll
            for (int r = 0; r < 4; r++) {
                const int m = m0 + wr * 64 + mi * 16 + quad * 4 + r;
                out[(size_t)m * CH + n] = acc[mi][ni][r];
            }
        }
    }
}

// ---------------------------------------------------------------------------
// Attention (fp32, unchanged math) — epilogue now writes bf16 y [B][T][C]
// ---------------------------------------------------------------------------
__global__ __launch_bounds__(256) void attn_kernel(
    const float* __restrict__ qw, const float* __restrict__ kw,
    const float* __restrict__ vw,
    const float* __restrict__ span_params, const float* __restrict__ stride_params,
    u16* __restrict__ yb)
{
    __shared__ float Ks[64][64];
    __shared__ float Vs[64][64];

    const int tid = threadIdx.x;
    const int g  = tid & 7;
    const int rl = tid >> 3;
    const int blk = blockIdx.x;
    const int it  = blk & 15;
    const int bh  = blk >> 4;
    const int h   = bh & (NH - 1);
    const int b   = bh >> 4;
    const int it0 = it << 6;

    const float span  = 1024.f / (1.f + __expf(-span_params[h]));
    const float limit = 32.f + span;
    const float e0 = __expf(stride_params[2 * h + 0]);
    const float e1 = __expf(stride_params[2 * h + 1]);
    const float inv_e = 1.f / (e0 + e1);
    const float sw0 = e0 * inv_e, sw1 = e1 * inv_e;

    const float* qg = qw + (size_t)bh * SEQ * HD;
    const float* kg = kw + (size_t)bh * SEQ * HD;
    const float* vg = vw + (size_t)bh * SEQ * HD;

    const int i0 = it0 + rl;
    const int i1 = it0 + rl + 32;

    float q0[8], q1[8];
    {
        const float4* p0 = (const float4*)&qg[(size_t)i0 * HD + g * 8];
        float4 a = p0[0], bb = p0[1];
        q0[0] = a.x; q0[1] = a.y; q0[2] = a.z; q0[3] = a.w;
        q0[4] = bb.x; q0[5] = bb.y; q0[6] = bb.z; q0[7] = bb.w;
        const float4* p1 = (const float4*)&qg[(size_t)i1 * HD + g * 8];
        float4 c = p1[0], dd = p1[1];
        q1[0] = c.x; q1[1] = c.y; q1[2] = c.z; q1[3] = c.w;
        q1[4] = dd.x; q1[5] = dd.y; q1[6] = dd.z; q1[7] = dd.w;
    }

    float acc0[8], acc1[8];
    #pragma unroll
    for (int i = 0; i < 8; i++) { acc0[i] = 0.f; acc1[i] = 0.f; }
    float sum0 = 0.f, sum1 = 0.f;

    int jmin = it0 - (int)limit - 1;
    if (jmin < 0) jmin = 0;
    const int jt0 = jmin & ~63;

    for (int jt = jt0; jt < it0 + 64; jt += 64) {
        __syncthreads();
        #pragma unroll
        for (int p = 0; p < 4; p++) {
            int o  = (tid + (p << 8)) << 2;
            int jj = o >> 6;
            int dd = o & 63;
            *(float4*)&Ks[jj][dd] = *(const float4*)&kg[(size_t)(jt + jj) * HD + dd];
            *(float4*)&Vs[jj][dd] = *(const float4*)&vg[(size_t)(jt + jj) * HD + dd];
        }
        __syncthreads();

        const int jend = min(jt + 64, it0 + 64);
        for (int j = jt; j < jend; ++j) {
            const int jj = j - jt;
            const float4* kr = (const float4*)&Ks[jj][g * 8];
            float4 ka = kr[0], kb = kr[1];
            float d0 = q0[0] * ka.x + q0[1] * ka.y + q0[2] * ka.z + q0[3] * ka.w
                     + q0[4] * kb.x + q0[5] * kb.y + q0[6] * kb.z + q0[7] * kb.w;
            float d1 = q1[0] * ka.x + q1[1] * ka.y + q1[2] * ka.z + q1[3] * ka.w
                     + q1[4] * kb.x + q1[5] * kb.y + q1[6] * kb.z + q1[7] * kb.w;
            d0 += __shfl_xor(d0, 1); d0 += __shfl_xor(d0, 2); d0 += __shfl_xor(d0, 4);
            d1 += __shfl_xor(d1, 1); d1 += __shfl_xor(d1, 2); d1 += __shfl_xor(d1, 4);

            float w0 = 0.f, w1 = 0.f;
            const int rel0 = i0 - j;
            if (rel0 >= 0) {
                float clipv = fminf(fmaxf((limit - (float)rel0) * (1.f / 32.f), 0.f), 1.f);
                float m2 = ((rel0 & 1) == 0) ? clipv : 0.f;
                w0 = __expf(d0 * 0.125f) * (sw0 * clipv + sw1 * m2);
            }
            const int rel1 = i1 - j;
            if (rel1 >= 0) {
                float clipv = fminf(fmaxf((limit - (float)rel1) * (1.f / 32.f), 0.f), 1.f);
                float m2 = ((rel1 & 1) == 0) ? clipv : 0.f;
                w1 = __expf(d1 * 0.125f) * (sw0 * clipv + sw1 * m2);
            }

            const float4* vr = (const float4*)&Vs[jj][g * 8];
            float4 va = vr[0], vb = vr[1];
            acc0[0] = fmaf(w0, va.x, acc0[0]); acc0[1] = fmaf(w0, va.y, acc0[1]);
            acc0[2] = fmaf(w0, va.z, acc0[2]); acc0[3] = fmaf(w0, va.w, acc0[3]);
            acc0[4] = fmaf(w0, vb.x, acc0[4]); acc0[5] = fmaf(w0, vb.y, acc0[5]);
            acc0[6] = fmaf(w0, vb.z, acc0[6]); acc0[7] = fmaf(w0, vb.w, acc0[7]);
            acc1[0] = fmaf(w1, va.x, acc1[0]); acc1[1] = fmaf(w1, va.y, acc1[1]);
            acc1[2] = fmaf(w1, va.z, acc1[2]); acc1[3] = fmaf(w1, va.w, acc1[3]);
            acc1[4] = fmaf(w1, vb.x, acc1[4]); acc1[5] = fmaf(w1, vb.y, acc1[5]);
            acc1[6] = fmaf(w1, vb.z, acc1[6]); acc1[7] = fmaf(w1, vb.w, acc1[7]);
            sum0 += w0; sum1 += w1;
        }
    }

    const float r0 = 1.f / sum0;
    const float r1 = 1.f / sum1;
    const size_t base0 = ((size_t)(b * SEQ + i0)) * CH + h * HD + g * 8;
    const size_t base1 = ((size_t)(b * SEQ + i1)) * CH + h * HD + g * 8;
    int4 pk0, pk1;
    pk0.x = (int)(f2bf(acc0[0] * r0) | (f2bf(acc0[1] * r0) << 16));
    pk0.y = (int)(f2bf(acc0[2] * r0) | (f2bf(acc0[3] * r0) << 16));
    pk0.z = (int)(f2bf(acc0[4] * r0) | (f2bf(acc0[5] * r0) << 16));
    pk0.w = (int)(f2bf(acc0[6] * r0) | (f2bf(acc0[7] * r0) << 16));
    pk1.x = (int)(f2bf(acc1[0] * r1) | (f2bf(acc1[1] * r1) << 16));
    pk1.y = (int)(f2bf(acc1[2] * r1) | (f2bf(acc1[3] * r1) << 16));
    pk1.z = (int)(f2bf(acc1[4] * r1) | (f2bf(acc1[5] * r1) << 16));
    pk1.w = (int)(f2bf(acc1[6] * r1) | (f2bf(acc1[7] * r1) << 16));
    *(int4*)&yb[base0] = pk0;
    *(int4*)&yb[base1] = pk1;
}

__global__ void span_loss_kernel(const float* __restrict__ sp, float* __restrict__ out)
{
    if (threadIdx.x == 0 && blockIdx.x == 0) {
        float s = 0.f;
        for (int h = 0; h < NH; h++) {
            float sig = 1.f / (1.f + __expf(-sp[h]));
            s += sig * 1024.f;
        }
        out[0] = 2e-6f * s / (float)NH;
    }
}

extern "C" void kernel_launch(void* const* d_in, const int* in_sizes, int n_in,
                              void* d_out, int out_size, void* d_ws, size_t ws_size,
                              hipStream_t stream)
{
    const float* x            = (const float*)d_in[0];
    const float* Wqkv         = (const float*)d_in[1];
    const float* Wproj        = (const float*)d_in[2];
    const float* span_params  = (const float*)d_in[3];
    const float* stride_param = (const float*)d_in[4];
    float* out = (float*)d_out;

    float* ws = (float*)d_ws;
    const size_t SZ = (size_t)BATCH * NH * SEQ * HD;  // 4,194,304
    float* qw = ws;
    float* kw = ws + SZ;
    float* vw = ws + 2 * SZ;
    u16* ub   = (u16*)(ws + 3 * SZ);
    u16* xb   = ub;                 // 4M u16 (8MB) — dead after gemm_qkv
    u16* yb   = ub;                 // aliases xb (written by attn, after gemm_qkv)
    u16* wqT  = ub + SZ;            // 3M u16 (6MB)  [3072][1024]
    u16* wpT  = wqT + (size_t)CH * N3;  // 1M u16 (2MB) [1024][1024]

    conv_bf16_kernel<<<dim3((int)(SZ / (256 * 8))), 256, 0, stream>>>(x, xb, (int)SZ);
    transpose_conv_kernel<<<dim3(N3 / 32, CH / 32), 256, 0, stream>>>(Wqkv, wqT, CH, N3);
    transpose_conv_kernel<<<dim3(CH / 32, CH / 32), 256, 0, stream>>>(Wproj, wpT, CH, CH);

    gemm_qkv_mfma<<<dim3(N3 / 128, (BATCH * SEQ) / 128), 256, 0, stream>>>(
        xb, wqT, qw, kw, vw);

    attn_kernel<<<dim3(BATCH * NH * (SEQ / 64)), 256, 0, stream>>>(
        qw, kw, vw, span_params, stride_param, yb);

    gemm_proj_mfma<<<dim3(CH / 128, (BATCH * SEQ) / 128), 256, 0, stream>>>(
        yb, wpT, out);

    span_loss_kernel<<<1, 64, 0, stream>>>(span_params, out + SZ);
}

// Round 3
// 194.606 us; speedup vs baseline: 4.3204x; 2.3651x over previous
//
#include <hip/hip_runtime.h>
#include <math.h>

#define BATCH 4
#define SEQ   1024
#define CH    1024
#define NH    16
#define HD    64
#define N3    3072

typedef unsigned short u16;
typedef unsigned int   u32;
typedef __attribute__((ext_vector_type(8))) __bf16 bf16x8;
typedef __attribute__((ext_vector_type(4))) float  f32x4;
typedef __attribute__((ext_vector_type(4))) u32    u32x4;

__device__ __forceinline__ u32 f2bf(float f) {
    u32 x = __float_as_uint(f);
    return (x + 0x7fffu + ((x >> 16) & 1u)) >> 16;   // RNE bf16
}

// ---------------------------------------------------------------------------
// fp32 -> bf16 elementwise (8 elems/thread)
// ---------------------------------------------------------------------------
__global__ __launch_bounds__(256) void conv_bf16_kernel(
    const float* __restrict__ in, u16* __restrict__ out, int n)
{
    int i = (blockIdx.x * 256 + threadIdx.x) * 8;
    if (i >= n) return;
    float4 a = *(const float4*)&in[i];
    float4 b = *(const float4*)&in[i + 4];
    int4 p;
    p.x = (int)(f2bf(a.x) | (f2bf(a.y) << 16));
    p.y = (int)(f2bf(a.z) | (f2bf(a.w) << 16));
    p.z = (int)(f2bf(b.x) | (f2bf(b.y) << 16));
    p.w = (int)(f2bf(b.z) | (f2bf(b.w) << 16));
    *(int4*)&out[i] = p;
}

// ---------------------------------------------------------------------------
// W [K][N] fp32 -> WT [N][K] bf16  (32x32 LDS tile transpose)
// ---------------------------------------------------------------------------
__global__ __launch_bounds__(256) void transpose_conv_kernel(
    const float* __restrict__ W, u16* __restrict__ WT, int K, int N)
{
    __shared__ float tile[32][33];
    const int n0 = blockIdx.x * 32, k0 = blockIdx.y * 32;
    const int tx = threadIdx.x & 31, ty = threadIdx.x >> 5;
    #pragma unroll
    for (int p = 0; p < 4; p++)
        tile[ty + p * 8][tx] = W[(size_t)(k0 + ty + p * 8) * N + n0 + tx];
    __syncthreads();
    #pragma unroll
    for (int p = 0; p < 4; p++)
        WT[(size_t)(n0 + ty + p * 8) * K + k0 + tx] = (u16)f2bf(tile[tx][ty + p * 8]);
}

// ---------------------------------------------------------------------------
// MFMA GEMM: 128x128 tile, 4 waves, BK=32, 16x16x32 bf16.
// qkv variant scatters bf16 into q/k/v [B][H][T][64].
// ---------------------------------------------------------------------------
__global__ __launch_bounds__(256) void gemm_qkv_mfma(
    const u16* __restrict__ A, const u16* __restrict__ BT,
    u16* __restrict__ qb, u16* __restrict__ kbuf, u16* __restrict__ vbuf)
{
    __shared__ __align__(16) u16 As[128 * 32];
    __shared__ __align__(16) u16 Bs[128 * 32];

    const int tid = threadIdx.x;
    const int lane = tid & 63;
    const int w = tid >> 6;
    const int wr = w >> 1, wc = w & 1;
    const int m0 = blockIdx.y * 128, n0 = blockIdx.x * 128;

    const int sr = tid >> 2;
    const int sc = (tid & 3) * 8;
    const u16* Ag0 = A  + (size_t)(m0 + sr) * CH + sc;
    const u16* Ag1 = A  + (size_t)(m0 + 64 + sr) * CH + sc;
    const u16* Bg0 = BT + (size_t)(n0 + sr) * CH + sc;
    const u16* Bg1 = BT + (size_t)(n0 + 64 + sr) * CH + sc;

    const int ln = lane & 15, quad = lane >> 4;
    const int afo = (wr * 64 + ln) * 32 + quad * 8;
    const int bfo = (wc * 64 + ln) * 32 + quad * 8;

    f32x4 acc[4][4];
    #pragma unroll
    for (int i = 0; i < 4; i++)
        #pragma unroll
        for (int j = 0; j < 4; j++) acc[i][j] = (f32x4)(0.f);

    for (int k0 = 0; k0 < CH; k0 += 32) {
        int4 a0 = *(const int4*)(Ag0 + k0);
        int4 a1 = *(const int4*)(Ag1 + k0);
        int4 b0 = *(const int4*)(Bg0 + k0);
        int4 b1 = *(const int4*)(Bg1 + k0);
        __syncthreads();
        *(int4*)&As[sr * 32 + sc]        = a0;
        *(int4*)&As[(sr + 64) * 32 + sc] = a1;
        *(int4*)&Bs[sr * 32 + sc]        = b0;
        *(int4*)&Bs[(sr + 64) * 32 + sc] = b1;
        __syncthreads();
        bf16x8 af[4], bfr[4];
        #pragma unroll
        for (int mi = 0; mi < 4; mi++) af[mi]  = *(const bf16x8*)&As[afo + mi * 512];
        #pragma unroll
        for (int ni = 0; ni < 4; ni++) bfr[ni] = *(const bf16x8*)&Bs[bfo + ni * 512];
        #pragma unroll
        for (int mi = 0; mi < 4; mi++)
            #pragma unroll
            for (int ni = 0; ni < 4; ni++)
                acc[mi][ni] = __builtin_amdgcn_mfma_f32_16x16x32_bf16(
                    af[mi], bfr[ni], acc[mi][ni], 0, 0, 0);
    }

    #pragma unroll
    for (int ni = 0; ni < 4; ni++) {
        const int n = n0 + wc * 64 + ni * 16 + ln;
        const int which = n >> 10;
        const int h = (n >> 6) & 15;
        const int d = n & 63;
        u16* dst = (which == 0) ? qb : (which == 1) ? kbuf : vbuf;
        #pragma unroll
        for (int mi = 0; mi < 4; mi++) {
            #pragma unroll
            for (int r = 0; r < 4; r++) {
                const int m = m0 + wr * 64 + mi * 16 + quad * 4 + r;
                const int b = m >> 10, t = m & 1023;
                dst[(((size_t)(b * NH + h)) * SEQ + t) * HD + d] =
                    (u16)f2bf(acc[mi][ni][r]);
            }
        }
    }
}

__global__ __launch_bounds__(256) void gemm_proj_mfma(
    const u16* __restrict__ A, const u16* __restrict__ BT, float* __restrict__ out)
{
    __shared__ __align__(16) u16 As[128 * 32];
    __shared__ __align__(16) u16 Bs[128 * 32];

    const int tid = threadIdx.x;
    const int lane = tid & 63;
    const int w = tid >> 6;
    const int wr = w >> 1, wc = w & 1;
    const int m0 = blockIdx.y * 128, n0 = blockIdx.x * 128;

    const int sr = tid >> 2;
    const int sc = (tid & 3) * 8;
    const u16* Ag0 = A  + (size_t)(m0 + sr) * CH + sc;
    const u16* Ag1 = A  + (size_t)(m0 + 64 + sr) * CH + sc;
    const u16* Bg0 = BT + (size_t)(n0 + sr) * CH + sc;
    const u16* Bg1 = BT + (size_t)(n0 + 64 + sr) * CH + sc;

    const int ln = lane & 15, quad = lane >> 4;
    const int afo = (wr * 64 + ln) * 32 + quad * 8;
    const int bfo = (wc * 64 + ln) * 32 + quad * 8;

    f32x4 acc[4][4];
    #pragma unroll
    for (int i = 0; i < 4; i++)
        #pragma unroll
        for (int j = 0; j < 4; j++) acc[i][j] = (f32x4)(0.f);

    for (int k0 = 0; k0 < CH; k0 += 32) {
        int4 a0 = *(const int4*)(Ag0 + k0);
        int4 a1 = *(const int4*)(Ag1 + k0);
        int4 b0 = *(const int4*)(Bg0 + k0);
        int4 b1 = *(const int4*)(Bg1 + k0);
        __syncthreads();
        *(int4*)&As[sr * 32 + sc]        = a0;
        *(int4*)&As[(sr + 64) * 32 + sc] = a1;
        *(int4*)&Bs[sr * 32 + sc]        = b0;
        *(int4*)&Bs[(sr + 64) * 32 + sc] = b1;
        __syncthreads();
        bf16x8 af[4], bfr[4];
        #pragma unroll
        for (int mi = 0; mi < 4; mi++) af[mi]  = *(const bf16x8*)&As[afo + mi * 512];
        #pragma unroll
        for (int ni = 0; ni < 4; ni++) bfr[ni] = *(const bf16x8*)&Bs[bfo + ni * 512];
        #pragma unroll
        for (int mi = 0; mi < 4; mi++)
            #pragma unroll
            for (int ni = 0; ni < 4; ni++)
                acc[mi][ni] = __builtin_amdgcn_mfma_f32_16x16x32_bf16(
                    af[mi], bfr[ni], acc[mi][ni], 0, 0, 0);
    }

    #pragma unroll
    for (int ni = 0; ni < 4; ni++) {
        const int n = n0 + wc * 64 + ni * 16 + ln;
        #pragma unroll
        for (int mi = 0; mi < 4; mi++) {
            #pragma unroll
            for (int r = 0; r < 4; r++) {
                const int m = m0 + wr * 64 + mi * 16 + quad * 4 + r;
                out[(size_t)m * CH + n] = acc[mi][ni][r];
            }
        }
    }
}

// ---------------------------------------------------------------------------
// MFMA flash attention. Block = (bh, 64-row Q tile), 4 waves x 16 rows.
// No online softmax (matches reference: exp without max-subtraction).
// Row sums via MFMA with B=ones. Mask via per-h LDS table over rel=i-j.
// ---------------------------------------------------------------------------
__global__ __launch_bounds__(256) void attn_mfma_kernel(
    const u16* __restrict__ qg, const u16* __restrict__ kg,
    const u16* __restrict__ vg,
    const float* __restrict__ span_params, const float* __restrict__ stride_params,
    u16* __restrict__ yb)
{
    __shared__ float tab[1056];               // rel+32 -> mask weight
    __shared__ u32   VTs[64 * 33];            // V^T packed pairs: [d][jp], stride 33
    __shared__ __align__(16) u16 Ps[4 * 16 * 72];  // per-wave P tiles, stride 72

    const int tid  = threadIdx.x;
    const int lane = tid & 63;
    const int w    = tid >> 6;
    const int ln   = lane & 15, quad = lane >> 4;

    const int blk = blockIdx.x;
    const int it  = blk & 15;
    const int bh  = blk >> 4;
    const int h   = bh & (NH - 1);
    const int b   = bh >> 4;
    const int it0 = it << 6;
    const int row_base = it0 + (w << 4);

    const float span  = 1024.f / (1.f + __expf(-span_params[h]));
    const float limit = 32.f + span;
    const float e0 = __expf(stride_params[2 * h + 0]);
    const float e1 = __expf(stride_params[2 * h + 1]);
    const float inv_e = 1.f / (e0 + e1);
    const float sw0 = e0 * inv_e, sw1 = e1 * inv_e;

    // mask weight table: tab[rel+32], rel in [-32, 1023]
    for (int i = tid; i < 1056; i += 256) {
        int rel = i - 32;
        float clipv = fminf(fmaxf((limit - (float)rel) * (1.f / 32.f), 0.f), 1.f);
        float mw = (rel < 0) ? 0.f : clipv * (sw0 + ((rel & 1) ? 0.f : sw1));
        tab[i] = mw;
    }

    const size_t hb = (size_t)bh * SEQ;

    // Q A-frags: register-resident for the whole block
    const u16* qp = qg + (hb + row_base + ln) * HD + quad * 8;
    bf16x8 aq0 = *(const bf16x8*)qp;
    bf16x8 aq1 = *(const bf16x8*)(qp + 32);

    // ones B-frag for row sums
    u32x4 onesw; onesw.x = onesw.y = onesw.z = onesw.w = 0x3f803f80u;
    const bf16x8 onesf = __builtin_bit_cast(bf16x8, onesw);

    f32x4 acc_o[4];
    #pragma unroll
    for (int di = 0; di < 4; di++) acc_o[di] = (f32x4)(0.f);
    f32x4 acc_s = (f32x4)(0.f);

    int jmin = it0 - (int)limit - 1;
    if (jmin < 0) jmin = 0;
    const int jt0 = jmin & ~63;

    // V staging decomposition
    const int dc = tid & 7, jp = tid >> 3;      // dc: 8-elem d-chunk, jp: j-pair

    u16* Psw = &Ps[w * 16 * 72];

    __syncthreads();   // table ready

    for (int jt = jt0; jt <= it0; jt += 64) {
        // ---- stage V^T (packed j-pairs) ----
        const u16* vp = vg + (hb + jt + 2 * jp) * HD + dc * 8;
        int4 v0 = *(const int4*)vp;
        int4 v1 = *(const int4*)(vp + HD);
        __syncthreads();   // previous iteration's VT reads complete
        {
            u32 a, bb;
            a = (u32)v0.x; bb = (u32)v1.x;
            VTs[(8 * dc + 0) * 33 + jp] = (a & 0xffffu) | (bb << 16);
            VTs[(8 * dc + 1) * 33 + jp] = (a >> 16) | (bb & 0xffff0000u);
            a = (u32)v0.y; bb = (u32)v1.y;
            VTs[(8 * dc + 2) * 33 + jp] = (a & 0xffffu) | (bb << 16);
            VTs[(8 * dc + 3) * 33 + jp] = (a >> 16) | (bb & 0xffff0000u);
            a = (u32)v0.z; bb = (u32)v1.z;
            VTs[(8 * dc + 4) * 33 + jp] = (a & 0xffffu) | (bb << 16);
            VTs[(8 * dc + 5) * 33 + jp] = (a >> 16) | (bb & 0xffff0000u);
            a = (u32)v0.w; bb = (u32)v1.w;
            VTs[(8 * dc + 6) * 33 + jp] = (a & 0xffffu) | (bb << 16);
            VTs[(8 * dc + 7) * 33 + jp] = (a >> 16) | (bb & 0xffff0000u);
        }

        // ---- S = Q K^T, mask+exp, P -> LDS (per-wave region, no barrier) ----
        #pragma unroll
        for (int ni = 0; ni < 4; ni++) {
            const int col0 = jt + ni * 16;
            const int rel_max = row_base + 15 - col0;
            const int rel_min = row_base - (col0 + 15);
            if (rel_max < 0 || (float)rel_min >= limit) {
                #pragma unroll
                for (int r = 0; r < 4; r++)
                    Psw[(quad * 4 + r) * 72 + ni * 16 + ln] = 0;
                continue;
            }
            const u16* kp = kg + (hb + col0 + ln) * HD + quad * 8;
            bf16x8 bk0 = *(const bf16x8*)kp;
            bf16x8 bk1 = *(const bf16x8*)(kp + 32);
            f32x4 s = __builtin_amdgcn_mfma_f32_16x16x32_bf16(aq0, bk0, (f32x4)(0.f), 0, 0, 0);
            s = __builtin_amdgcn_mfma_f32_16x16x32_bf16(aq1, bk1, s, 0, 0, 0);
            #pragma unroll
            for (int r = 0; r < 4; r++) {
                const int rel = (row_base + quad * 4 + r) - (col0 + ln);
                float wv = __expf(s[r] * 0.125f) * tab[rel + 32];
                Psw[(quad * 4 + r) * 72 + ni * 16 + ln] = (u16)f2bf(wv);
            }
        }

        __syncthreads();   // VT visible to all waves

        // ---- O += P V, rowsum += P 1 ----
        bf16x8 ap0 = *(const bf16x8*)&Psw[ln * 72 + quad * 8];
        bf16x8 ap1 = *(const bf16x8*)&Psw[ln * 72 + 32 + quad * 8];
        acc_s = __builtin_amdgcn_mfma_f32_16x16x32_bf16(ap0, onesf, acc_s, 0, 0, 0);
        acc_s = __builtin_amdgcn_mfma_f32_16x16x32_bf16(ap1, onesf, acc_s, 0, 0, 0);
        #pragma unroll
        for (int di = 0; di < 4; di++) {
            const int base0 = (di * 16 + ln) * 33 + quad * 4;
            u32x4 c0, c1;
            c0.x = VTs[base0 + 0]; c0.y = VTs[base0 + 1];
            c0.z = VTs[base0 + 2]; c0.w = VTs[base0 + 3];
            c1.x = VTs[base0 + 16]; c1.y = VTs[base0 + 17];
            c1.z = VTs[base0 + 18]; c1.w = VTs[base0 + 19];
            bf16x8 bv0 = __builtin_bit_cast(bf16x8, c0);
            bf16x8 bv1 = __builtin_bit_cast(bf16x8, c1);
            acc_o[di] = __builtin_amdgcn_mfma_f32_16x16x32_bf16(ap0, bv0, acc_o[di], 0, 0, 0);
            acc_o[di] = __builtin_amdgcn_mfma_f32_16x16x32_bf16(ap1, bv1, acc_o[di], 0, 0, 0);
        }
    }

    // ---- normalize + write y bf16 [B][T][C] ----
    #pragma unroll
    for (int r = 0; r < 4; r++) {
        const int t = row_base + quad * 4 + r;
        const float inv = 1.f / acc_s[r];
        const size_t rowoff = ((size_t)(b * SEQ + t)) * CH + h * HD;
        #pragma unroll
        for (int di = 0; di < 4; di++)
            yb[rowoff + di * 16 + ln] = (u16)f2bf(acc_o[di][r] * inv);
    }
}

__global__ void span_loss_kernel(const float* __restrict__ sp, float* __restrict__ out)
{
    if (threadIdx.x == 0 && blockIdx.x == 0) {
        float s = 0.f;
        for (int h = 0; h < NH; h++) {
            float sig = 1.f / (1.f + __expf(-sp[h]));
            s += sig * 1024.f;
        }
        out[0] = 2e-6f * s / (float)NH;
    }
}

extern "C" void kernel_launch(void* const* d_in, const int* in_sizes, int n_in,
                              void* d_out, int out_size, void* d_ws, size_t ws_size,
                              hipStream_t stream)
{
    const float* x            = (const float*)d_in[0];
    const float* Wqkv         = (const float*)d_in[1];
    const float* Wproj        = (const float*)d_in[2];
    const float* span_params  = (const float*)d_in[3];
    const float* stride_param = (const float*)d_in[4];
    float* out = (float*)d_out;

    const size_t SZ = (size_t)BATCH * NH * SEQ * HD;  // 4,194,304
    u16* base = (u16*)d_ws;
    u16* qb  = base;                    // bf16 [B][H][T][64]
    u16* kb  = qb + SZ;
    u16* vb  = kb + SZ;
    u16* yb  = vb + SZ;                 // bf16 [B][T][C]
    u16* xb  = yb + SZ;                 // bf16 x
    u16* wqT = xb + SZ;                 // bf16 [3072][1024]
    u16* wpT = wqT + (size_t)CH * N3;   // bf16 [1024][1024]

    conv_bf16_kernel<<<dim3((int)(SZ / (256 * 8))), 256, 0, stream>>>(x, xb, (int)SZ);
    transpose_conv_kernel<<<dim3(N3 / 32, CH / 32), 256, 0, stream>>>(Wqkv, wqT, CH, N3);
    transpose_conv_kernel<<<dim3(CH / 32, CH / 32), 256, 0, stream>>>(Wproj, wpT, CH, CH);

    gemm_qkv_mfma<<<dim3(N3 / 128, (BATCH * SEQ) / 128), 256, 0, stream>>>(
        xb, wqT, qb, kb, vb);

    attn_mfma_kernel<<<dim3(BATCH * NH * (SEQ / 64)), 256, 0, stream>>>(
        qb, kb, vb, span_params, stride_param, yb);

    gemm_proj_mfma<<<dim3(CH / 128, (BATCH * SEQ) / 128), 256, 0, stream>>>(
        yb, wpT, out);

    span_loss_kernel<<<1, 64, 0, stream>>>(span_params, out + SZ);
}